// Round 5
// baseline (385.346 us; speedup 1.0000x reference)
//
#include <hip/hip_runtime.h>

#define NIN 64
#define NOUT 32
#define KK 9
#define NBUCK 65536

typedef __attribute__((ext_vector_type(8))) short bf16x8;
typedef __attribute__((ext_vector_type(16))) float f32x16;

// fp32 -> bf16 round-to-nearest-even
__device__ __forceinline__ unsigned short f2bf_rne(float f) {
    unsigned int u = __builtin_bit_cast(unsigned int, f);
    unsigned int r = (u + 0x7FFFu + ((u >> 16) & 1u)) >> 16;
    return (unsigned short)r;
}
__device__ __forceinline__ float bf2f(unsigned short h) {
    unsigned int u = ((unsigned int)h) << 16;
    return __builtin_bit_cast(float, u);
}

// ---------------------------------------------------------------------------
// Kernel 0: pre-pack weights into MFMA B-fragment layout, split bf16 hi/lo.
__global__ void mink_prep_w(const float* __restrict__ w,
                            unsigned short* __restrict__ wf) {
    int t = blockIdx.x * 256 + threadIdx.x;
    if (t >= KK * 4 * 64) return;
    int l = t & 63, ks = (t >> 6) & 3, k = t >> 8;
    int col = l & 31;
    int kb = ks * 16 + (l >> 5) * 4;
    #pragma unroll
    for (int j = 0; j < 8; ++j) {
        int c = kb + (j & 3) + 8 * (j >> 2);
        float v = w[(k * NIN + c) * NOUT + col];
        unsigned short hi = f2bf_rne(v);
        unsigned short lo = f2bf_rne(v - bf2f(hi));
        wf[(size_t)((k * 4 + ks) * 64 + l) * 8 + j] = hi;
        wf[(size_t)(KK * 4 * 64 * 8) + (size_t)((k * 4 + ks) * 64 + l) * 8 + j] = lo;
    }
}

// ---------------------------------------------------------------------------
// Sort machinery: bucket sites by center output row (out_idx[n][4] >> shift).
// np.unique assigns rows in sorted coord order, so row ~ spatial position;
// grouping by row range gives the atomic scatter L2 temporal locality.
__global__ void mink_zero_hist(int* __restrict__ hist) {
    int i = blockIdx.x * 256 + threadIdx.x;
    if (i < NBUCK) hist[i] = 0;
}

__global__ void mink_hist(const int* __restrict__ oidx, int* __restrict__ hist,
                          int n, int shift) {
    int i = blockIdx.x * 256 + threadIdx.x;
    if (i < n) atomicAdd(&hist[oidx[(size_t)i * KK + 4] >> shift], 1);
}

// single-block exclusive scan of NBUCK counters (in place)
__global__ __launch_bounds__(256) void mink_scan(int* __restrict__ hist) {
    __shared__ int tsum[256];
    int t = threadIdx.x;
    int base = t * (NBUCK / 256);
    int s = 0;
    for (int i = 0; i < NBUCK / 256; ++i) s += hist[base + i];
    tsum[t] = s;
    __syncthreads();
    if (t == 0) {
        int run = 0;
        for (int i = 0; i < 256; ++i) { int v = tsum[i]; tsum[i] = run; run += v; }
    }
    __syncthreads();
    int run = tsum[t];
    for (int i = 0; i < NBUCK / 256; ++i) {
        int v = hist[base + i];
        hist[base + i] = run;
        run += v;
    }
}

__global__ void mink_scatter_perm(const int* __restrict__ oidx,
                                  int* __restrict__ ofs, int* __restrict__ perm,
                                  int n, int shift) {
    int i = blockIdx.x * 256 + threadIdx.x;
    if (i < n) {
        int b = oidx[(size_t)i * KK + 4] >> shift;
        int p = atomicAdd(&ofs[b], 1);
        perm[p] = i;
    }
}

// ---------------------------------------------------------------------------
// Kernel 1: initialize every output row with the bias.
__global__ void mink_init_bias(float4* __restrict__ out,
                               const float4* __restrict__ bias, int n4) {
    int i = blockIdx.x * blockDim.x + threadIdx.x;
    if (i < n4) {
        out[i] = bias[i & 7];
    }
}

// ---------------------------------------------------------------------------
// Kernel 2: one wave per 32-site tile of the PERMUTED site list. Split-bf16
// MFMA computes the 32x32 contribution tile per kernel offset; atomics now
// have row locality (sorted sites -> clustered rows -> L2-hit RMWs).
__global__ __launch_bounds__(256) void mink_scatter_mfma(
    const float* __restrict__ feats,       // [N, 64] f32
    const unsigned short* __restrict__ wf, // packed bf16 frags (hi, lo)
    const int* __restrict__ out_idx,       // [N, 9]
    const int* __restrict__ perm,          // [N] sorted site order
    float* __restrict__ out,               // [num_out, 32]
    int ntiles) {
    int wid  = (blockIdx.x * 256 + threadIdx.x) >> 6;
    int lane = threadIdx.x & 63;
    if (wid >= ntiles) return;
    int n0   = wid * 32;
    int half = lane >> 5;
    int col  = lane & 31;

    int site = perm[n0 + col];   // lanes l and l+32 hold the same site

    // preload this site's 9 output rows (k-loop is fully unrolled -> static idx)
    int idx9[KK];
    const int* ip = out_idx + (size_t)site * KK;
    #pragma unroll
    for (int j = 0; j < KK; ++j) idx9[j] = ip[j];

    // ---- A fragments: fp32 feats -> split bf16 in-register.
    const float* xrow = feats + (size_t)site * NIN;
    int kbase = half * 4;
    bf16x8 ahi[4], alo[4];
    #pragma unroll
    for (int ks = 0; ks < 4; ++ks) {
        float4 v0 = *(const float4*)(xrow + ks * 16 + kbase);
        float4 v1 = *(const float4*)(xrow + ks * 16 + kbase + 8);
        float xs[8] = {v0.x, v0.y, v0.z, v0.w, v1.x, v1.y, v1.z, v1.w};
        #pragma unroll
        for (int j = 0; j < 8; ++j) {
            unsigned short h = f2bf_rne(xs[j]);
            ahi[ks][j] = (short)h;
            alo[ks][j] = (short)f2bf_rne(xs[j] - bf2f(h));
        }
    }

    const bf16x8* wfh = (const bf16x8*)wf;
    const bf16x8* wfl = wfh + KK * 4 * 64;

    #pragma unroll   // FULL unroll so idx9[k] is statically indexed
    for (int k = 0; k < KK; ++k) {
        f32x16 acc = {0,0,0,0,0,0,0,0,0,0,0,0,0,0,0,0};
        #pragma unroll
        for (int ks = 0; ks < 4; ++ks) {
            bf16x8 bh = wfh[(k * 4 + ks) * 64 + lane];
            bf16x8 bl = wfl[(k * 4 + ks) * 64 + lane];
            acc = __builtin_amdgcn_mfma_f32_32x32x16_bf16(ahi[ks], bh, acc, 0, 0, 0);
            acc = __builtin_amdgcn_mfma_f32_32x32x16_bf16(ahi[ks], bl, acc, 0, 0, 0);
            acc = __builtin_amdgcn_mfma_f32_32x32x16_bf16(alo[ks], bh, acc, 0, 0, 0);
        }
        // scatter: C/D layout col=lane&31, site=(r&3)+8*(r>>2)+4*half
        #pragma unroll
        for (int r = 0; r < 16; ++r) {
            int sidx = (r & 3) + 8 * (r >> 2) + 4 * half;  // tile-local site
            int row = __shfl(idx9[k], sidx, 64);           // from lane sidx
            unsafeAtomicAdd(out + (size_t)row * NOUT + col, acc[r]);
        }
    }
}

// ---------------------------------------------------------------------------
// Kernel 3: ReLU pass over the whole output.
__global__ void mink_relu(float4* __restrict__ out, int n4) {
    int i = blockIdx.x * blockDim.x + threadIdx.x;
    if (i < n4) {
        float4 v = out[i];
        v.x = fmaxf(v.x, 0.0f);
        v.y = fmaxf(v.y, 0.0f);
        v.z = fmaxf(v.z, 0.0f);
        v.w = fmaxf(v.w, 0.0f);
        out[i] = v;
    }
}

extern "C" void kernel_launch(void* const* d_in, const int* in_sizes, int n_in,
                              void* d_out, int out_size, void* d_ws, size_t ws_size,
                              hipStream_t stream) {
    const float* feats  = (const float*)d_in[0];  // [N, 64] f32
    const float* weight = (const float*)d_in[1];  // [9, 64, 32] f32
    const float* bias   = (const float*)d_in[2];  // [32] f32
    const int*   oidx   = (const int*)d_in[3];    // [N, 9] i32
    float* out = (float*)d_out;                   // [num_out, 32] f32

    int n  = in_sizes[0] / NIN;   // 262144
    int n4 = out_size / 4;
    int num_out = out_size / NOUT;

    // d_ws layout
    unsigned short* wf = (unsigned short*)d_ws;                 // 73728 B
    int* hist = (int*)((char*)d_ws + 73728);                    // NBUCK*4
    int* perm = (int*)((char*)d_ws + 73728 + NBUCK * 4);        // n*4

    int shift = 0;
    while (((num_out - 1) >> shift) >= NBUCK) ++shift;

    mink_prep_w<<<(KK * 4 * 64 + 255) / 256, 256, 0, stream>>>(weight, wf);
    mink_zero_hist<<<NBUCK / 256, 256, 0, stream>>>(hist);
    mink_hist<<<(n + 255) / 256, 256, 0, stream>>>(oidx, hist, n, shift);
    mink_scan<<<1, 256, 0, stream>>>(hist);
    mink_scatter_perm<<<(n + 255) / 256, 256, 0, stream>>>(oidx, hist, perm, n, shift);

    mink_init_bias<<<(n4 + 255) / 256, 256, 0, stream>>>(
        (float4*)out, (const float4*)bias, n4);

    int ntiles = n / 32;                       // 8192
    mink_scatter_mfma<<<ntiles * 64 / 256, 256, 0, stream>>>(
        feats, wf, oidx, perm, out, ntiles);

    mink_relu<<<(n4 + 255) / 256, 256, 0, stream>>>((float4*)out, n4);
}